// Round 4
// baseline (540.046 us; speedup 1.0000x reference)
//
#include <hip/hip_runtime.h>

typedef __bf16 bf16x8 __attribute__((ext_vector_type(8)));
typedef float f32x4 __attribute__((ext_vector_type(4)));

#define AS1 __attribute__((address_space(1)))
#define AS3 __attribute__((address_space(3)))

__device__ __forceinline__ void gload_lds16(const void* g, void* l) {
    __builtin_amdgcn_global_load_lds((const AS1 void*)g, (AS3 void*)l, 16, 0, 0);
}

__device__ __forceinline__ unsigned short f2bf(float f) {
    unsigned u = __builtin_bit_cast(unsigned, f);
    u += 0x7fffu + ((u >> 16) & 1u);
    return (unsigned short)(u >> 16);
}

// ---------------- fp32 -> bf16 convert (vectorized) ----------------
__global__ __launch_bounds__(256) void cvt_kernel(const float* __restrict__ src,
                                                  unsigned short* __restrict__ dst, int n4) {
    int i = blockIdx.x * 256 + threadIdx.x;
    if (i >= n4) return;
    float4 v = reinterpret_cast<const float4*>(src)[i];
    ushort4 o;
    o.x = f2bf(v.x); o.y = f2bf(v.y); o.z = f2bf(v.z); o.w = f2bf(v.w);
    reinterpret_cast<ushort4*>(dst)[i] = o;
}

// ---------------- fused QKV projection GEMM (m97 structure) ----------------
// C[row, col] = sum_k x[row,k] * W[col,k] + bias[col]   (B^T layout, both K-major)
// 128x128 tile, BK=32, 4 waves each 64x64 quadrant (4x4 16x16x32 frags).
// z=0 (Q): written [b*l][1024].  z=1,2 (K,V): written TRANSPOSED [b][h][d][l]
// (batch stride in rows is 1024 = h*64+d; bug in r3 used 16384 -> OOB fault).
__global__ __launch_bounds__(256) void gemm_qkv(
        const unsigned short* __restrict__ xb, const unsigned short* __restrict__ Wb,
        const float* __restrict__ bq, const float* __restrict__ bk, const float* __restrict__ bv,
        unsigned short* __restrict__ Qb, unsigned short* __restrict__ KTb,
        unsigned short* __restrict__ VTb) {
    __shared__ unsigned short lA[128 * 32];
    __shared__ unsigned short lB[128 * 32];
    const int tid = threadIdx.x, w = tid >> 6, lane = tid & 63;
    const int z = blockIdx.z;
    const unsigned short* W = Wb + (size_t)z * (1024 * 1024);
    const float* bias = (z == 0) ? bq : (z == 1 ? bk : bv);
    const int m0 = blockIdx.y * 128, n0 = blockIdx.x * 128;
    const int srow = lane >> 2, scol = (lane & 3) * 8;   // staging: 16 rows x 32 cols per issue
    const int l15 = lane & 15, quad = lane >> 4;
    const int wm = w >> 1, wn = w & 1;
    f32x4 acc[4][4] = {};
    for (int k0 = 0; k0 < 1024; k0 += 32) {
        __syncthreads();
#pragma unroll
        for (int i = 0; i < 2; i++) {
            int t = w * 2 + i;   // issue index 0..7, covers rows t*16..t*16+15
            gload_lds16(xb + (size_t)(m0 + t * 16 + srow) * 1024 + k0 + scol,
                        (char*)lA + t * 1024);
            gload_lds16(W + (size_t)(n0 + t * 16 + srow) * 1024 + k0 + scol,
                        (char*)lB + t * 1024);
        }
        __syncthreads();
        bf16x8 af[4], bfr[4];
#pragma unroll
        for (int mi = 0; mi < 4; mi++)
            af[mi] = *(const bf16x8*)&lA[(wm * 64 + mi * 16 + l15) * 32 + quad * 8];
#pragma unroll
        for (int ni = 0; ni < 4; ni++)
            bfr[ni] = *(const bf16x8*)&lB[(wn * 64 + ni * 16 + l15) * 32 + quad * 8];
#pragma unroll
        for (int mi = 0; mi < 4; mi++)
#pragma unroll
            for (int ni = 0; ni < 4; ni++)
                acc[mi][ni] = __builtin_amdgcn_mfma_f32_16x16x32_bf16(af[mi], bfr[ni],
                                                                      acc[mi][ni], 0, 0, 0);
    }
    // epilogue: C layout col=lane&15, row=quad*4+reg
    if (z == 0) {
#pragma unroll
        for (int ni = 0; ni < 4; ni++) {
            int col = n0 + wn * 64 + ni * 16 + l15;
            float bias_v = bias[col];
#pragma unroll
            for (int mi = 0; mi < 4; mi++) {
                int row = m0 + wm * 64 + mi * 16 + quad * 4;
#pragma unroll
                for (int r = 0; r < 4; r++)
                    Qb[(size_t)(row + r) * 1024 + col] = f2bf(acc[mi][ni][r] + bias_v);
            }
        }
    } else {
        unsigned short* T = (z == 1) ? KTb : VTb;
#pragma unroll
        for (int ni = 0; ni < 4; ni++) {
            int col = n0 + wn * 64 + ni * 16 + l15;   // = h*64 + d
            float bias_v = bias[col];
#pragma unroll
            for (int mi = 0; mi < 4; mi++) {
                int row = m0 + wm * 64 + mi * 16 + quad * 4;   // = b*4096 + l
                int b = row >> 12, l = row & 4095;
                ushort4 o;
                o.x = f2bf(acc[mi][ni][0] + bias_v);
                o.y = f2bf(acc[mi][ni][1] + bias_v);
                o.z = f2bf(acc[mi][ni][2] + bias_v);
                o.w = f2bf(acc[mi][ni][3] + bias_v);
                *(ushort4*)&T[((size_t)b * 1024 + col) * 4096 + l] = o;
            }
        }
    }
}

// ---------------- Kp = E @ K, VpT = (E @ V)^T  per (b,h), split-K over L ----------------
// K/V already transposed to [b][h][d][l]; all fragments are contiguous 16B global loads.
// Grid (bh=64, split=16); each block covers L range of 256 (8 chunks of 32).
// fp32 partials accumulated with atomicAdd (buffers zeroed by memset before launch).
__global__ __launch_bounds__(256) void kpvp_kernel(
        const unsigned short* __restrict__ KTb, const unsigned short* __restrict__ VTb,
        const unsigned short* __restrict__ Eb,
        float* __restrict__ KpF, float* __restrict__ VpF) {
    const int tid = threadIdx.x, w = tid >> 6, lane = tid & 63;
    const int l15 = lane & 15, quad = lane >> 4;
    const int bh = blockIdx.x, h = bh & 15;
    const int Ls = blockIdx.y * 256;
    const unsigned short* KT = KTb + (size_t)bh * 64 * 4096;   // [d][l]
    const unsigned short* VT = VTb + (size_t)bh * 64 * 4096;
    const unsigned short* Eh = Eb + (size_t)h * 128 * 4096;    // [kk][l]
    f32x4 accV[8] = {};
    f32x4 accK[2][4] = {};
    for (int s = 0; s < 8; s++) {
        const int l0 = Ls + s * 32;
        // E fragments: row kt*16+l15, 8 contiguous l.  A-op for Kp, B-op for Vp.
        bf16x8 ef[8];
#pragma unroll
        for (int kt = 0; kt < 8; kt++)
            ef[kt] = *(const bf16x8*)&Eh[(size_t)(kt * 16 + l15) * 4096 + l0 + quad * 8];
        // VpT[d][kk]: A = V^T row (w*16+l15)
        bf16x8 av = *(const bf16x8*)&VT[(size_t)(w * 16 + l15) * 4096 + l0 + quad * 8];
#pragma unroll
        for (int kt = 0; kt < 8; kt++)
            accV[kt] = __builtin_amdgcn_mfma_f32_16x16x32_bf16(av, ef[kt], accV[kt], 0, 0, 0);
        // Kp[kk][d]: B = K^T rows nt*16+l15
        bf16x8 bkf[4];
#pragma unroll
        for (int nt = 0; nt < 4; nt++)
            bkf[nt] = *(const bf16x8*)&KT[(size_t)(nt * 16 + l15) * 4096 + l0 + quad * 8];
#pragma unroll
        for (int mi = 0; mi < 2; mi++)
#pragma unroll
            for (int nt = 0; nt < 4; nt++)
                accK[mi][nt] = __builtin_amdgcn_mfma_f32_16x16x32_bf16(ef[w * 2 + mi], bkf[nt],
                                                                       accK[mi][nt], 0, 0, 0);
    }
#pragma unroll
    for (int kt = 0; kt < 8; kt++) {
        int d = w * 16 + quad * 4;
        int kk = kt * 16 + l15;
#pragma unroll
        for (int r = 0; r < 4; r++)
            atomicAdd(&VpF[((size_t)bh * 64 + d + r) * 128 + kk], accV[kt][r]);
    }
#pragma unroll
    for (int mi = 0; mi < 2; mi++) {
        int kk = (w * 2 + mi) * 16 + quad * 4;
#pragma unroll
        for (int nt = 0; nt < 4; nt++) {
            int d = nt * 16 + l15;
#pragma unroll
            for (int r = 0; r < 4; r++)
                atomicAdd(&KpF[((size_t)bh * 128 + kk + r) * 64 + d], accK[mi][nt][r]);
        }
    }
}

// ---------------- attention: dot -> softmax -> PV -> out ----------------
// Block: 4 waves x 16 query rows; full k=128 context per wave.
__global__ __launch_bounds__(256) void attn_kernel(
        const unsigned short* __restrict__ Qb, const unsigned short* __restrict__ Kpb,
        const unsigned short* __restrict__ VpTb, float* __restrict__ out) {
    __shared__ unsigned short P[4 * 16 * 136];   // per-wave P tile, stride 136 (pad)
    const int tid = threadIdx.x, w = tid >> 6, lane = tid & 63;
    const int l15 = lane & 15, quad = lane >> 4;
    const int bh = blockIdx.y, b = bh >> 4, h = bh & 15;
    const int l0 = blockIdx.x * 64 + w * 16;
    const unsigned short* Qrow = Qb + (size_t)(b * 4096 + l0 + l15) * 1024 + h * 64;
    bf16x8 aq0 = *(const bf16x8*)&Qrow[quad * 8];
    bf16x8 aq1 = *(const bf16x8*)&Qrow[32 + quad * 8];
    const unsigned short* Kp = Kpb + (size_t)bh * 128 * 64;
    f32x4 acc[8];
#pragma unroll
    for (int kt = 0; kt < 8; kt++) {
        const unsigned short* kr = Kp + (size_t)(kt * 16 + l15) * 64;
        bf16x8 b0 = *(const bf16x8*)&kr[quad * 8];
        bf16x8 b1 = *(const bf16x8*)&kr[32 + quad * 8];
        f32x4 a = {};
        a = __builtin_amdgcn_mfma_f32_16x16x32_bf16(aq0, b0, a, 0, 0, 0);
        a = __builtin_amdgcn_mfma_f32_16x16x32_bf16(aq1, b1, a, 0, 0, 0);
        acc[kt] = a;
    }
    // softmax over 128 cols; row = quad*4+r, cols spread over (kt, lane&15)
    const float scale = 0.125f;
    float pr[8][4];
#pragma unroll
    for (int r = 0; r < 4; r++) {
        float m = -1e30f;
#pragma unroll
        for (int kt = 0; kt < 8; kt++) m = fmaxf(m, acc[kt][r]);
#pragma unroll
        for (int off = 8; off >= 1; off >>= 1) m = fmaxf(m, __shfl_xor(m, off, 64));
        float s = 0.f;
#pragma unroll
        for (int kt = 0; kt < 8; kt++) {
            float e = __expf(scale * (acc[kt][r] - m));
            pr[kt][r] = e;
            s += e;
        }
#pragma unroll
        for (int off = 8; off >= 1; off >>= 1) s += __shfl_xor(s, off, 64);
        float rinv = 1.0f / s;
#pragma unroll
        for (int kt = 0; kt < 8; kt++) pr[kt][r] *= rinv;
    }
    // P -> LDS (C layout) -> A layout
    unsigned short* Pw = &P[w * 16 * 136];
#pragma unroll
    for (int kt = 0; kt < 8; kt++)
#pragma unroll
        for (int r = 0; r < 4; r++)
            Pw[(quad * 4 + r) * 136 + kt * 16 + l15] = f2bf(pr[kt][r]);
    __syncthreads();
    bf16x8 ap[4];
#pragma unroll
    for (int t = 0; t < 4; t++)
        ap[t] = *(const bf16x8*)&Pw[l15 * 136 + t * 32 + quad * 8];
    const unsigned short* Vp = VpTb + (size_t)bh * 64 * 128;
    f32x4 acco[4] = {};
#pragma unroll
    for (int nt = 0; nt < 4; nt++) {
        const unsigned short* vr = Vp + (size_t)(nt * 16 + l15) * 128;
#pragma unroll
        for (int t = 0; t < 4; t++) {
            bf16x8 bv = *(const bf16x8*)&vr[t * 32 + quad * 8];
            acco[nt] = __builtin_amdgcn_mfma_f32_16x16x32_bf16(ap[t], bv, acco[nt], 0, 0, 0);
        }
    }
#pragma unroll
    for (int nt = 0; nt < 4; nt++) {
        int col = h * 64 + nt * 16 + l15;
#pragma unroll
        for (int r = 0; r < 4; r++)
            out[(size_t)(b * 4096 + l0 + quad * 4 + r) * 1024 + col] = acco[nt][r];
    }
}

extern "C" void kernel_launch(void* const* d_in, const int* in_sizes, int n_in,
                              void* d_out, int out_size, void* d_ws, size_t ws_size,
                              hipStream_t stream) {
    const float* x  = (const float*)d_in[0];
    const float* Wq = (const float*)d_in[1];
    const float* bq = (const float*)d_in[2];
    const float* Wk = (const float*)d_in[3];
    const float* bk = (const float*)d_in[4];
    const float* Wv = (const float*)d_in[5];
    const float* bv = (const float*)d_in[6];
    const float* E  = (const float*)d_in[7];
    float* out = (float*)d_out;
    char* ws = (char*)d_ws;

    // workspace layout (bytes)
    unsigned short* xb   = (unsigned short*)(ws);              // 33,554,432  (reused for Eb)
    unsigned short* Wb   = (unsigned short*)(ws + 33554432);   //  6,291,456  (reused for KpF/VpF)
    unsigned short* Qb   = (unsigned short*)(ws + 39845888);   // 33,554,432
    unsigned short* KTb  = (unsigned short*)(ws + 73400320);   // 33,554,432  [b][h][d][l]
    unsigned short* VTb  = (unsigned short*)(ws + 106954752);  // 33,554,432  [b][h][d][l]
    unsigned short* Kpb  = (unsigned short*)(ws + 140509184);  //  1,048,576
    unsigned short* VpTb = (unsigned short*)(ws + 141557760);  //  1,048,576
    unsigned short* Eb   = xb;                                 // alias: x dead after GEMM
    float* KpF = (float*)(ws + 33554432);                      // 2 MB, aliases Wb (dead after GEMM)
    float* VpF = KpF + 524288;                                 // 2 MB
    if (ws_size < 142606336) return;

    cvt_kernel<<<16384, 256, 0, stream>>>(x, xb, 4194304);
    cvt_kernel<<<1024, 256, 0, stream>>>(Wq, Wb, 262144);
    cvt_kernel<<<1024, 256, 0, stream>>>(Wk, Wb + 1048576, 262144);
    cvt_kernel<<<1024, 256, 0, stream>>>(Wv, Wb + 2097152, 262144);
    gemm_qkv<<<dim3(8, 128, 3), 256, 0, stream>>>(xb, Wb, bq, bk, bv, Qb, KTb, VTb);
    cvt_kernel<<<8192, 256, 0, stream>>>(E, Eb, 2097152);
    hipMemsetAsync(KpF, 0, 4194304, stream);
    kpvp_kernel<<<dim3(64, 16), 256, 0, stream>>>(KTb, VTb, Eb, KpF, VpF);
    cvt_kernel<<<1024, 256, 0, stream>>>(KpF, Kpb, 262144);  // converts KpF+VpF -> Kpb+VpTb (contiguous)
    attn_kernel<<<dim3(64, 64), 256, 0, stream>>>(Qb, Kpb, VpTb, out);
}

// Round 5
// 530.101 us; speedup vs baseline: 1.0188x; 1.0188x over previous
//
#include <hip/hip_runtime.h>

typedef __bf16 bf16x8 __attribute__((ext_vector_type(8)));
typedef float f32x4 __attribute__((ext_vector_type(4)));

#define AS1 __attribute__((address_space(1)))
#define AS3 __attribute__((address_space(3)))

__device__ __forceinline__ void gload_lds16(const void* g, void* l) {
    __builtin_amdgcn_global_load_lds((const AS1 void*)g, (AS3 void*)l, 16, 0, 0);
}

__device__ __forceinline__ unsigned short f2bf(float f) {
    unsigned u = __builtin_bit_cast(unsigned, f);
    u += 0x7fffu + ((u >> 16) & 1u);
    return (unsigned short)(u >> 16);
}

// ---------------- fp32 -> bf16 convert (vectorized) ----------------
__global__ __launch_bounds__(256) void cvt_kernel(const float* __restrict__ src,
                                                  unsigned short* __restrict__ dst, int n4) {
    int i = blockIdx.x * 256 + threadIdx.x;
    if (i >= n4) return;
    float4 v = reinterpret_cast<const float4*>(src)[i];
    ushort4 o;
    o.x = f2bf(v.x); o.y = f2bf(v.y); o.z = f2bf(v.z); o.w = f2bf(v.w);
    reinterpret_cast<ushort4*>(dst)[i] = o;
}

// ---------------- fused QKV projection GEMM ----------------
// C[row, col] = sum_k x[row,k] * W[col,k] + bias[col]   (B^T layout, both K-major)
// 128x128 tile, BK=64 as two 32-col panels (keeps stride-32 conflict-free LDS +
// global_load_lds contiguity), 4 waves each 64x64 quadrant, 32 MFMA/wave/iter.
// z=0 (Q): [b*l][1024].  z=1,2 (K,V): TRANSPOSED [b][h][d][l] (batch row-stride 1024).
__global__ __launch_bounds__(256) void gemm_qkv(
        const unsigned short* __restrict__ xb, const unsigned short* __restrict__ Wb,
        const float* __restrict__ bq, const float* __restrict__ bk, const float* __restrict__ bv,
        unsigned short* __restrict__ Qb, unsigned short* __restrict__ KTb,
        unsigned short* __restrict__ VTb) {
    __shared__ unsigned short lA[2 * 128 * 32];   // [s][row][32]
    __shared__ unsigned short lB[2 * 128 * 32];
    const int tid = threadIdx.x, w = tid >> 6, lane = tid & 63;
    const int z = blockIdx.z;
    const unsigned short* W = Wb + (size_t)z * (1024 * 1024);
    const float* bias = (z == 0) ? bq : (z == 1 ? bk : bv);
    const int m0 = blockIdx.y * 128, n0 = blockIdx.x * 128;
    const int srow = lane >> 2, scol = (lane & 3) * 8;   // 16 rows x 32 cols per issue
    const int l15 = lane & 15, quad = lane >> 4;
    const int wm = w >> 1, wn = w & 1;
    f32x4 acc[4][4] = {};
    for (int k0 = 0; k0 < 1024; k0 += 64) {
        __syncthreads();
#pragma unroll
        for (int s = 0; s < 2; s++) {
#pragma unroll
            for (int i = 0; i < 2; i++) {
                int t = w * 2 + i;   // 0..7 -> rows t*16..t*16+15
                gload_lds16(xb + (size_t)(m0 + t * 16 + srow) * 1024 + k0 + s * 32 + scol,
                            (char*)lA + (s * 8192 + t * 1024));
                gload_lds16(W + (size_t)(n0 + t * 16 + srow) * 1024 + k0 + s * 32 + scol,
                            (char*)lB + (s * 8192 + t * 1024));
            }
        }
        __syncthreads();
#pragma unroll
        for (int s = 0; s < 2; s++) {
            bf16x8 af[4], bfr[4];
#pragma unroll
            for (int mi = 0; mi < 4; mi++)
                af[mi] = *(const bf16x8*)&lA[(s * 128 + wm * 64 + mi * 16 + l15) * 32 + quad * 8];
#pragma unroll
            for (int ni = 0; ni < 4; ni++)
                bfr[ni] = *(const bf16x8*)&lB[(s * 128 + wn * 64 + ni * 16 + l15) * 32 + quad * 8];
#pragma unroll
            for (int mi = 0; mi < 4; mi++)
#pragma unroll
                for (int ni = 0; ni < 4; ni++)
                    acc[mi][ni] = __builtin_amdgcn_mfma_f32_16x16x32_bf16(af[mi], bfr[ni],
                                                                          acc[mi][ni], 0, 0, 0);
        }
    }
    // epilogue: C layout col=lane&15, row=quad*4+reg
    if (z == 0) {
#pragma unroll
        for (int ni = 0; ni < 4; ni++) {
            int col = n0 + wn * 64 + ni * 16 + l15;
            float bias_v = bias[col];
#pragma unroll
            for (int mi = 0; mi < 4; mi++) {
                int row = m0 + wm * 64 + mi * 16 + quad * 4;
#pragma unroll
                for (int r = 0; r < 4; r++)
                    Qb[(size_t)(row + r) * 1024 + col] = f2bf(acc[mi][ni][r] + bias_v);
            }
        }
    } else {
        unsigned short* T = (z == 1) ? KTb : VTb;
#pragma unroll
        for (int ni = 0; ni < 4; ni++) {
            int col = n0 + wn * 64 + ni * 16 + l15;   // = h*64 + d
            float bias_v = bias[col];
#pragma unroll
            for (int mi = 0; mi < 4; mi++) {
                int row = m0 + wm * 64 + mi * 16 + quad * 4;   // = b*4096 + l
                int b = row >> 12, l = row & 4095;
                ushort4 o;
                o.x = f2bf(acc[mi][ni][0] + bias_v);
                o.y = f2bf(acc[mi][ni][1] + bias_v);
                o.z = f2bf(acc[mi][ni][2] + bias_v);
                o.w = f2bf(acc[mi][ni][3] + bias_v);
                *(ushort4*)&T[((size_t)b * 1024 + col) * 4096 + l] = o;
            }
        }
    }
}

// ---------------- Kp = E @ K, VpT = (E @ V)^T  per (b,h), split over L ----------------
// m97-style LDS staging: E tile [128][32] shared as Kp-A-operand AND Vp-B-operand,
// KT/VT tiles [64][32]; all staged via global_load_lds (coalesced 128B-line fetches).
// Grid (bh=64, split=8); each block covers L range of 512 (16 chunks of 32).
// fp32 partials accumulated with atomicAdd (buffers zeroed by memset before launch).
__global__ __launch_bounds__(256) void kpvp_kernel(
        const unsigned short* __restrict__ KTb, const unsigned short* __restrict__ VTb,
        const unsigned short* __restrict__ Eb,
        float* __restrict__ KpF, float* __restrict__ VpF) {
    __shared__ unsigned short Esh[128 * 32];   // 8 KB
    __shared__ unsigned short Ksh[64 * 32];    // 4 KB
    __shared__ unsigned short Vsh[64 * 32];    // 4 KB
    const int tid = threadIdx.x, w = tid >> 6, lane = tid & 63;
    const int l15 = lane & 15, quad = lane >> 4;
    const int bh = blockIdx.x, h = bh & 15;
    const int Ls = blockIdx.y * 512;
    const int srow = lane >> 2, scol = (lane & 3) * 8;
    const unsigned short* KT = KTb + (size_t)bh * 64 * 4096;   // [d][l]
    const unsigned short* VT = VTb + (size_t)bh * 64 * 4096;
    const unsigned short* Eh = Eb + (size_t)h * 128 * 4096;    // [kk][l]
    f32x4 accV[8] = {};
    f32x4 accK[2][4] = {};
    for (int s = 0; s < 16; s++) {
        const int l0 = Ls + s * 32;
        __syncthreads();
#pragma unroll
        for (int i = 0; i < 2; i++) {
            int t = w * 2 + i;   // 0..7 -> E rows t*16..t*16+15
            gload_lds16(Eh + (size_t)(t * 16 + srow) * 4096 + l0 + scol,
                        (char*)Esh + t * 1024);
        }
        gload_lds16(KT + (size_t)(w * 16 + srow) * 4096 + l0 + scol, (char*)Ksh + w * 1024);
        gload_lds16(VT + (size_t)(w * 16 + srow) * 4096 + l0 + scol, (char*)Vsh + w * 1024);
        __syncthreads();
        // E fragments (rows kt*16+l15): A-op for Kp, B-op for Vp.
        bf16x8 ef[8];
#pragma unroll
        for (int kt = 0; kt < 8; kt++)
            ef[kt] = *(const bf16x8*)&Esh[(kt * 16 + l15) * 32 + quad * 8];
        // VpT[d][kk]: A = V^T row (w*16+l15), B = E
        bf16x8 av = *(const bf16x8*)&Vsh[(w * 16 + l15) * 32 + quad * 8];
#pragma unroll
        for (int kt = 0; kt < 8; kt++)
            accV[kt] = __builtin_amdgcn_mfma_f32_16x16x32_bf16(av, ef[kt], accV[kt], 0, 0, 0);
        // Kp[kk][d]: A = E rows (w*2+mi), B = K^T rows nt*16+l15
        bf16x8 bkf[4];
#pragma unroll
        for (int nt = 0; nt < 4; nt++)
            bkf[nt] = *(const bf16x8*)&Ksh[(nt * 16 + l15) * 32 + quad * 8];
#pragma unroll
        for (int mi = 0; mi < 2; mi++)
#pragma unroll
            for (int nt = 0; nt < 4; nt++)
                accK[mi][nt] = __builtin_amdgcn_mfma_f32_16x16x32_bf16(ef[w * 2 + mi], bkf[nt],
                                                                       accK[mi][nt], 0, 0, 0);
    }
#pragma unroll
    for (int kt = 0; kt < 8; kt++) {
        int d = w * 16 + quad * 4;
        int kk = kt * 16 + l15;
#pragma unroll
        for (int r = 0; r < 4; r++)
            atomicAdd(&VpF[((size_t)bh * 64 + d + r) * 128 + kk], accV[kt][r]);
    }
#pragma unroll
    for (int mi = 0; mi < 2; mi++) {
        int kk = (w * 2 + mi) * 16 + quad * 4;
#pragma unroll
        for (int nt = 0; nt < 4; nt++) {
            int d = nt * 16 + l15;
#pragma unroll
            for (int r = 0; r < 4; r++)
                atomicAdd(&KpF[((size_t)bh * 128 + kk + r) * 64 + d], accK[mi][nt][r]);
        }
    }
}

// ---------------- attention: dot -> softmax -> PV -> out ----------------
// Block: 4 waves x 16 query rows; full k=128 context per wave.
__global__ __launch_bounds__(256) void attn_kernel(
        const unsigned short* __restrict__ Qb, const unsigned short* __restrict__ Kpb,
        const unsigned short* __restrict__ VpTb, float* __restrict__ out) {
    __shared__ unsigned short P[4 * 16 * 136];   // per-wave P tile, stride 136 (pad)
    const int tid = threadIdx.x, w = tid >> 6, lane = tid & 63;
    const int l15 = lane & 15, quad = lane >> 4;
    const int bh = blockIdx.y, b = bh >> 4, h = bh & 15;
    const int l0 = blockIdx.x * 64 + w * 16;
    const unsigned short* Qrow = Qb + (size_t)(b * 4096 + l0 + l15) * 1024 + h * 64;
    bf16x8 aq0 = *(const bf16x8*)&Qrow[quad * 8];
    bf16x8 aq1 = *(const bf16x8*)&Qrow[32 + quad * 8];
    const unsigned short* Kp = Kpb + (size_t)bh * 128 * 64;
    f32x4 acc[8];
#pragma unroll
    for (int kt = 0; kt < 8; kt++) {
        const unsigned short* kr = Kp + (size_t)(kt * 16 + l15) * 64;
        bf16x8 b0 = *(const bf16x8*)&kr[quad * 8];
        bf16x8 b1 = *(const bf16x8*)&kr[32 + quad * 8];
        f32x4 a = {};
        a = __builtin_amdgcn_mfma_f32_16x16x32_bf16(aq0, b0, a, 0, 0, 0);
        a = __builtin_amdgcn_mfma_f32_16x16x32_bf16(aq1, b1, a, 0, 0, 0);
        acc[kt] = a;
    }
    // softmax over 128 cols; row = quad*4+r, cols spread over (kt, lane&15)
    const float scale = 0.125f;
    float pr[8][4];
#pragma unroll
    for (int r = 0; r < 4; r++) {
        float m = -1e30f;
#pragma unroll
        for (int kt = 0; kt < 8; kt++) m = fmaxf(m, acc[kt][r]);
#pragma unroll
        for (int off = 8; off >= 1; off >>= 1) m = fmaxf(m, __shfl_xor(m, off, 64));
        float s = 0.f;
#pragma unroll
        for (int kt = 0; kt < 8; kt++) {
            float e = __expf(scale * (acc[kt][r] - m));
            pr[kt][r] = e;
            s += e;
        }
#pragma unroll
        for (int off = 8; off >= 1; off >>= 1) s += __shfl_xor(s, off, 64);
        float rinv = 1.0f / s;
#pragma unroll
        for (int kt = 0; kt < 8; kt++) pr[kt][r] *= rinv;
    }
    // P -> LDS (C layout) -> A layout
    unsigned short* Pw = &P[w * 16 * 136];
#pragma unroll
    for (int kt = 0; kt < 8; kt++)
#pragma unroll
        for (int r = 0; r < 4; r++)
            Pw[(quad * 4 + r) * 136 + kt * 16 + l15] = f2bf(pr[kt][r]);
    __syncthreads();
    bf16x8 ap[4];
#pragma unroll
    for (int t = 0; t < 4; t++)
        ap[t] = *(const bf16x8*)&Pw[l15 * 136 + t * 32 + quad * 8];
    const unsigned short* Vp = VpTb + (size_t)bh * 64 * 128;
    f32x4 acco[4] = {};
#pragma unroll
    for (int nt = 0; nt < 4; nt++) {
        const unsigned short* vr = Vp + (size_t)(nt * 16 + l15) * 128;
#pragma unroll
        for (int t = 0; t < 4; t++) {
            bf16x8 bv = *(const bf16x8*)&vr[t * 32 + quad * 8];
            acco[nt] = __builtin_amdgcn_mfma_f32_16x16x32_bf16(ap[t], bv, acco[nt], 0, 0, 0);
        }
    }
#pragma unroll
    for (int nt = 0; nt < 4; nt++) {
        int col = h * 64 + nt * 16 + l15;
#pragma unroll
        for (int r = 0; r < 4; r++)
            out[(size_t)(b * 4096 + l0 + quad * 4 + r) * 1024 + col] = acco[nt][r];
    }
}

extern "C" void kernel_launch(void* const* d_in, const int* in_sizes, int n_in,
                              void* d_out, int out_size, void* d_ws, size_t ws_size,
                              hipStream_t stream) {
    const float* x  = (const float*)d_in[0];
    const float* Wq = (const float*)d_in[1];
    const float* bq = (const float*)d_in[2];
    const float* Wk = (const float*)d_in[3];
    const float* bk = (const float*)d_in[4];
    const float* Wv = (const float*)d_in[5];
    const float* bv = (const float*)d_in[6];
    const float* E  = (const float*)d_in[7];
    float* out = (float*)d_out;
    char* ws = (char*)d_ws;

    // workspace layout (bytes)
    unsigned short* xb   = (unsigned short*)(ws);              // 33,554,432  (reused for Eb)
    unsigned short* Wb   = (unsigned short*)(ws + 33554432);   //  6,291,456  (reused for KpF/VpF)
    unsigned short* Qb   = (unsigned short*)(ws + 39845888);   // 33,554,432
    unsigned short* KTb  = (unsigned short*)(ws + 73400320);   // 33,554,432  [b][h][d][l]
    unsigned short* VTb  = (unsigned short*)(ws + 106954752);  // 33,554,432  [b][h][d][l]
    unsigned short* Kpb  = (unsigned short*)(ws + 140509184);  //  1,048,576
    unsigned short* VpTb = (unsigned short*)(ws + 141557760);  //  1,048,576
    unsigned short* Eb   = xb;                                 // alias: x dead after GEMM
    float* KpF = (float*)(ws + 33554432);                      // 2 MB, aliases Wb (dead after GEMM)
    float* VpF = KpF + 524288;                                 // 2 MB
    if (ws_size < 142606336) return;

    cvt_kernel<<<16384, 256, 0, stream>>>(x, xb, 4194304);
    cvt_kernel<<<1024, 256, 0, stream>>>(Wq, Wb, 262144);
    cvt_kernel<<<1024, 256, 0, stream>>>(Wk, Wb + 1048576, 262144);
    cvt_kernel<<<1024, 256, 0, stream>>>(Wv, Wb + 2097152, 262144);
    gemm_qkv<<<dim3(8, 128, 3), 256, 0, stream>>>(xb, Wb, bq, bk, bv, Qb, KTb, VTb);
    cvt_kernel<<<8192, 256, 0, stream>>>(E, Eb, 2097152);
    hipMemsetAsync(KpF, 0, 4194304, stream);
    kpvp_kernel<<<dim3(64, 8), 256, 0, stream>>>(KTb, VTb, Eb, KpF, VpF);
    cvt_kernel<<<1024, 256, 0, stream>>>(KpF, Kpb, 262144);  // KpF+VpF -> Kpb+VpTb (contiguous)
    attn_kernel<<<dim3(64, 64), 256, 0, stream>>>(Qb, Kpb, VpTb, out);
}